// Round 5
// baseline (81.909 us; speedup 1.0000x reference)
//
#include <hip/hip_runtime.h>
#include <cstdint>

#define NK 16384
#define NB 4096
#define NM 256
#define LOG2E 1.4426950408889634f
#define TWO_LOG2E 2.8853900817779268f

typedef __attribute__((ext_vector_type(8))) short short8;
typedef __attribute__((ext_vector_type(4))) float floatx4;

#if __has_builtin(__builtin_amdgcn_exp2f)
#define EXP2F(x) __builtin_amdgcn_exp2f(x)
#else
#define EXP2F(x) exp2f(x)
#endif

// Static device scratch: bf16 copy of x_basis [4096][256], per-center {W[n], ||c_n||^2*log2e}.
__device__ unsigned short g_xb[NB * NM];   // 2 MB (L2-resident per XCD)
__device__ float2 g_wc[NB];                // 32 KB

__device__ __forceinline__ unsigned short f2bf(float f) {
    unsigned int u = __float_as_uint(f);
    u += 0x7FFFu + ((u >> 16) & 1u);       // RTN-even
    return (unsigned short)(u >> 16);
}

// One wave per x_basis row: convert 256 fp32 -> bf16, compute ||c||^2 * log2e.
__global__ __launch_bounds__(256) void rbf_prep(const float* __restrict__ xb,
                                                const float* __restrict__ W) {
    const int row  = blockIdx.x * 4 + (threadIdx.x >> 6);
    const int lane = threadIdx.x & 63;
    const float4 v = ((const float4*)(xb + row * NM))[lane];
    float ss = v.x * v.x + v.y * v.y + v.z * v.z + v.w * v.w;
    #pragma unroll
    for (int m = 1; m < 64; m <<= 1) ss += __shfl_xor(ss, m, 64);
    ushort4 o;
    o.x = f2bf(v.x); o.y = f2bf(v.y); o.z = f2bf(v.z); o.w = f2bf(v.w);
    *(ushort4*)(g_xb + row * NM + lane * 4) = o;
    if (lane == 0) g_wc[row] = make_float2(W[row], ss * LOG2E);
}

// Stage one 16-center tile (16 x 256 bf16 = 8KB) into this wave's LDS buffer.
// LDS dest linear (HW: uniform base + lane*16); bank-conflict swizzle applied on the
// GLOBAL source side (chunk ^= row&7); ds_read applies the same involution.
#define STAGE(t, bufIdx)                                                              \
    {                                                                                 \
        _Pragma("unroll")                                                             \
        for (int j = 0; j < 8; ++j) {                                                 \
            const int q  = j * 64 + lane;      /* 16B-chunk index within tile */      \
            const int rr = q >> 5;             /* center row 0..15 */                 \
            const int cc = q & 31;             /* 16B chunk within row */             \
            const unsigned short* srcp =                                              \
                g_xb + (n0 + (t) * 16 + rr) * NM + ((cc ^ (rr & 7)) * 8);             \
            unsigned short* dstp = &Bt[w][bufIdx][j * 512];                           \
            __builtin_amdgcn_global_load_lds(                                         \
                (const __attribute__((address_space(1))) void*)srcp,                  \
                (__attribute__((address_space(3))) void*)dstp, 16, 0, 0);             \
        }                                                                             \
    }

// ---- A prologue helpers: NAMED fragments only (no runtime-indexed arrays).
#define LOADFRAG(dst, s)                                                              \
    {                                                                                 \
        const float4 f0 = xr4[(s) * 8 + g * 2];                                       \
        const float4 f1 = xr4[(s) * 8 + g * 2 + 1];                                   \
        ss += f0.x * f0.x + f0.y * f0.y + f0.z * f0.z + f0.w * f0.w                   \
            + f1.x * f1.x + f1.y * f1.y + f1.z * f1.z + f1.w * f1.w;                  \
        short8 t;                                                                     \
        t[0] = (short)f2bf(f0.x); t[1] = (short)f2bf(f0.y);                           \
        t[2] = (short)f2bf(f0.z); t[3] = (short)f2bf(f0.w);                           \
        t[4] = (short)f2bf(f1.x); t[5] = (short)f2bf(f1.y);                           \
        t[6] = (short)f2bf(f1.z); t[7] = (short)f2bf(f1.w);                           \
        dst = t;                                                                      \
    }

#define LOADROW(rt, A0, A1, A2, A3, A4, A5, A6, A7)                                   \
    {                                                                                 \
        const float4* xr4 = (const float4*)(x + (row0 + (rt) * 16 + r) * NM);         \
        float ss = 0.f;                                                               \
        LOADFRAG(A0, 0) LOADFRAG(A1, 1) LOADFRAG(A2, 2) LOADFRAG(A3, 3)               \
        LOADFRAG(A4, 4) LOADFRAG(A5, 5) LOADFRAG(A6, 6) LOADFRAG(A7, 7)               \
        ss += __shfl_xor(ss, 16, 64);                                                 \
        ss += __shfl_xor(ss, 32, 64);                                                 \
        if (w == 0 && g == 0) xsl[(rt) * 16 + r] = ss * LOG2E;                        \
    }

// One K=32 step across all 4 row-tiles: 1 ds_read_b128 -> 4 MFMA. s must be a literal.
#define CSTEP(s)                                                                      \
    {                                                                                 \
        const short8 b =                                                              \
            *(const short8*)(bp + r * 256 + ((((s) * 4 + g) ^ (r & 7)) * 8));         \
        c0 = __builtin_amdgcn_mfma_f32_16x16x32_bf16(af0##s, b, c0, 0, 0, 0);         \
        c1 = __builtin_amdgcn_mfma_f32_16x16x32_bf16(af1##s, b, c1, 0, 0, 0);         \
        c2 = __builtin_amdgcn_mfma_f32_16x16x32_bf16(af2##s, b, c2, 0, 0, 0);         \
        c3 = __builtin_amdgcn_mfma_f32_16x16x32_bf16(af3##s, b, c3, 0, 0, 0);         \
    }

#define EPI1(cc, xsv, acref)                                                          \
    acref = fmaf(EXP2F(fmaf(cc, TWO_LOG2E, nb - (xsv))), wgt, acref);

// One 16-center tile: 8 ds_read_b128 -> 32 MFMA -> fused exp/W epilogue (all static).
#define COMPUTE(bufIdx, wcv)                                                          \
    {                                                                                 \
        const unsigned short* bp = &Bt[w][bufIdx][0];                                 \
        floatx4 c0 = {0.f, 0.f, 0.f, 0.f}, c1 = {0.f, 0.f, 0.f, 0.f};                 \
        floatx4 c2 = {0.f, 0.f, 0.f, 0.f}, c3 = {0.f, 0.f, 0.f, 0.f};                 \
        CSTEP(0) CSTEP(1) CSTEP(2) CSTEP(3) CSTEP(4) CSTEP(5) CSTEP(6) CSTEP(7)       \
        const float nb  = -(wcv).y;                                                   \
        const float wgt = (wcv).x;                                                    \
        EPI1(c0[0], xs0.x, ac0.x) EPI1(c0[1], xs0.y, ac0.y)                           \
        EPI1(c0[2], xs0.z, ac0.z) EPI1(c0[3], xs0.w, ac0.w)                           \
        EPI1(c1[0], xs1.x, ac1.x) EPI1(c1[1], xs1.y, ac1.y)                           \
        EPI1(c1[2], xs1.z, ac1.z) EPI1(c1[3], xs1.w, ac1.w)                           \
        EPI1(c2[0], xs2.x, ac2.x) EPI1(c2[1], xs2.y, ac2.y)                           \
        EPI1(c2[2], xs2.z, ac2.z) EPI1(c2[3], xs2.w, ac2.w)                           \
        EPI1(c3[0], xs3.x, ac3.x) EPI1(c3[1], xs3.y, ac3.y)                           \
        EPI1(c3[2], xs3.z, ac3.z) EPI1(c3[3], xs3.w, ac3.w)                           \
    }

#define RED(val, rt, j)                                                               \
    {                                                                                 \
        float v = (val);                                                              \
        v += __shfl_xor(v, 1, 64); v += __shfl_xor(v, 2, 64);                         \
        v += __shfl_xor(v, 4, 64); v += __shfl_xor(v, 8, 64);                         \
        if (r == 0) rowacc[w][(rt) * 16 + g * 4 + (j)] = v;                           \
    }

// 256 blocks (1/CU), 512 threads (8 waves). Block owns 64 rows; wave w owns ALL
// 4 row-tiles (A in 128 named-VGPR fragments) x centers [w*512, (w+1)*512).
// No main-loop barriers; per-wave counted vmcnt(9) double-buffer pipeline.
//
// VGPR budget fix: R2-R4 allocated exactly 128 VGPRs and spilled 512 B/thread
// (WRITE_SIZE 66MB). 128 = 512-reg SIMD file / 4 waves -- the budget for the
// DEFAULT flat-work-group-size of 1024 threads, i.e. __launch_bounds__ never
// reached the backend. Set the backend attributes explicitly: 512-thread WG
// (8 waves -> 2 waves/SIMD) + waves_per_eu(2,2) -> 256-VGPR budget, no spill.
// Occupancy unchanged (LDS 130KB already caps at 1 block/CU).
__global__ void
__attribute__((amdgpu_flat_work_group_size(512, 512), amdgpu_waves_per_eu(2, 2)))
rbf_main(const float* __restrict__ x,
         const float* __restrict__ bptr,
         float* __restrict__ out) {
    __shared__ __align__(16) unsigned short Bt[8][2][16 * NM];  // 128 KB
    __shared__ float xsl[64];
    __shared__ float rowacc[8][64];

    const int tid  = threadIdx.x;
    const int w    = tid >> 6;
    const int lane = tid & 63;
    const int r    = lane & 15;
    const int g    = lane >> 4;
    const int row0 = blockIdx.x * 64;
    const int n0   = w * 512;

    short8 af00, af01, af02, af03, af04, af05, af06, af07;
    short8 af10, af11, af12, af13, af14, af15, af16, af17;
    short8 af20, af21, af22, af23, af24, af25, af26, af27;
    short8 af30, af31, af32, af33, af34, af35, af36, af37;

    LOADROW(0, af00, af01, af02, af03, af04, af05, af06, af07)
    LOADROW(1, af10, af11, af12, af13, af14, af15, af16, af17)
    LOADROW(2, af20, af21, af22, af23, af24, af25, af26, af27)
    LOADROW(3, af30, af31, af32, af33, af34, af35, af36, af37)
    __syncthreads();

    // per-lane ||x||^2*log2e for this lane's C/D rows: rt*16 + g*4 + {0..3}
    const float4 xs0 = *(const float4*)&xsl[0 * 16 + g * 4];
    const float4 xs1 = *(const float4*)&xsl[1 * 16 + g * 4];
    const float4 xs2 = *(const float4*)&xsl[2 * 16 + g * 4];
    const float4 xs3 = *(const float4*)&xsl[3 * 16 + g * 4];

    float4 ac0 = {0.f, 0.f, 0.f, 0.f};
    float4 ac1 = {0.f, 0.f, 0.f, 0.f};
    float4 ac2 = {0.f, 0.f, 0.f, 0.f};
    float4 ac3 = {0.f, 0.f, 0.f, 0.f};

    // prologue: tile 0 + wc 0 in flight (9 vmem ops outstanding at loop top)
    STAGE(0, 0);
    float2 wcA = g_wc[n0 + r];
    float2 wcB;

    #pragma unroll 1
    for (int i = 0; i < 32; i += 2) {
        // ---- iter i: consume buf0/wcA, prefetch tile i+1 -> buf1 ----
        wcB = g_wc[n0 + ((i + 1) & 31) * 16 + r];
        STAGE((i + 1) & 31, 1);
        asm volatile("s_waitcnt vmcnt(9)" ::: "memory");  // tile i + wc_i drained
        __builtin_amdgcn_sched_barrier(0);
        COMPUTE(0, wcA);
        // ---- iter i+1: consume buf1/wcB, prefetch tile i+2 -> buf0 ----
        wcA = g_wc[n0 + ((i + 2) & 31) * 16 + r];
        STAGE((i + 2) & 31, 0);
        asm volatile("s_waitcnt vmcnt(9)" ::: "memory");
        __builtin_amdgcn_sched_barrier(0);
        COMPUTE(1, wcB);
    }

    // ---- reduce over the 16 column-lanes; combine 8 waves' N-partials ----
    RED(ac0.x, 0, 0) RED(ac0.y, 0, 1) RED(ac0.z, 0, 2) RED(ac0.w, 0, 3)
    RED(ac1.x, 1, 0) RED(ac1.y, 1, 1) RED(ac1.z, 1, 2) RED(ac1.w, 1, 3)
    RED(ac2.x, 2, 0) RED(ac2.y, 2, 1) RED(ac2.z, 2, 2) RED(ac2.w, 2, 3)
    RED(ac3.x, 3, 0) RED(ac3.y, 3, 1) RED(ac3.z, 3, 2) RED(ac3.w, 3, 3)
    __syncthreads();

    if (tid < 64) {
        float logit = bptr[0];
        #pragma unroll
        for (int ww = 0; ww < 8; ++ww) logit += rowacc[ww][tid];
        out[row0 + tid] = 1.f / (1.f + EXP2F(-logit * LOG2E));
    }
}

extern "C" void kernel_launch(void* const* d_in, const int* in_sizes, int n_in,
                              void* d_out, int out_size, void* d_ws, size_t ws_size,
                              hipStream_t stream) {
    const float* x  = (const float*)d_in[0];   // [16384,256]
    const float* xb = (const float*)d_in[1];   // [4096,256]
    const float* W  = (const float*)d_in[2];   // [1,4096]
    const float* b  = (const float*)d_in[3];   // [1]
    float* out = (float*)d_out;                // [16384,1]

    rbf_prep<<<dim3(NB / 4), dim3(256), 0, stream>>>(xb, W);
    rbf_main<<<dim3(NK / 64), dim3(512), 0, stream>>>(x, b, out);
}

// Round 6
// 62.305 us; speedup vs baseline: 1.3146x; 1.3146x over previous
//
#include <hip/hip_runtime.h>
#include <cstdint>

#define NK 16384
#define NB 4096
#define NM 256
#define LOG2E 1.4426950408889634f
#define TWO_LOG2E 2.8853900817779268f

typedef __attribute__((ext_vector_type(8))) short short8;
typedef __attribute__((ext_vector_type(4))) float floatx4;

#if __has_builtin(__builtin_amdgcn_exp2f)
#define EXP2F(x) __builtin_amdgcn_exp2f(x)
#else
#define EXP2F(x) exp2f(x)
#endif

// Static device scratch: bf16 copy of x_basis [4096][256], per-center {W[n], ||c_n||^2*log2e}.
__device__ unsigned short g_xb[NB * NM];   // 2 MB (L2-resident per XCD)
__device__ float2 g_wc[NB];                // 32 KB

__device__ __forceinline__ unsigned short f2bf(float f) {
    unsigned int u = __float_as_uint(f);
    u += 0x7FFFu + ((u >> 16) & 1u);       // RTN-even
    return (unsigned short)(u >> 16);
}

// One wave per x_basis row: convert 256 fp32 -> bf16, compute ||c||^2 * log2e.
__global__ __launch_bounds__(256) void rbf_prep(const float* __restrict__ xb,
                                                const float* __restrict__ W) {
    const int row  = blockIdx.x * 4 + (threadIdx.x >> 6);
    const int lane = threadIdx.x & 63;
    const float4 v = ((const float4*)(xb + row * NM))[lane];
    float ss = v.x * v.x + v.y * v.y + v.z * v.z + v.w * v.w;
    #pragma unroll
    for (int m = 1; m < 64; m <<= 1) ss += __shfl_xor(ss, m, 64);
    ushort4 o;
    o.x = f2bf(v.x); o.y = f2bf(v.y); o.z = f2bf(v.z); o.w = f2bf(v.w);
    *(ushort4*)(g_xb + row * NM + lane * 4) = o;
    if (lane == 0) g_wc[row] = make_float2(W[row], ss * LOG2E);
}

// Stage one 16-center tile (16 x 256 bf16 = 8KB) into this wave's LDS buffer.
// LDS dest linear (HW: uniform base + lane*16); bank-conflict swizzle applied on the
// GLOBAL source side (chunk ^= row&7); ds_read applies the same involution.
#define STAGE(t, bufIdx)                                                              \
    {                                                                                 \
        _Pragma("unroll")                                                             \
        for (int j = 0; j < 8; ++j) {                                                 \
            const int q  = j * 64 + lane;      /* 16B-chunk index within tile */      \
            const int rr = q >> 5;             /* center row 0..15 */                 \
            const int cc = q & 31;             /* 16B chunk within row */             \
            const unsigned short* srcp =                                              \
                g_xb + (n0 + (t) * 16 + rr) * NM + ((cc ^ (rr & 7)) * 8);             \
            unsigned short* dstp = &Bt[w][bufIdx][j * 512];                           \
            __builtin_amdgcn_global_load_lds(                                         \
                (const __attribute__((address_space(1))) void*)srcp,                  \
                (__attribute__((address_space(3))) void*)dstp, 16, 0, 0);             \
        }                                                                             \
    }

// ---- A prologue helpers: NAMED fragments only (no runtime-indexed arrays).
#define LOADFRAG(dst, s)                                                              \
    {                                                                                 \
        const float4 f0 = xr4[(s) * 8 + g * 2];                                       \
        const float4 f1 = xr4[(s) * 8 + g * 2 + 1];                                   \
        ss += f0.x * f0.x + f0.y * f0.y + f0.z * f0.z + f0.w * f0.w                   \
            + f1.x * f1.x + f1.y * f1.y + f1.z * f1.z + f1.w * f1.w;                  \
        short8 t;                                                                     \
        t[0] = (short)f2bf(f0.x); t[1] = (short)f2bf(f0.y);                           \
        t[2] = (short)f2bf(f0.z); t[3] = (short)f2bf(f0.w);                           \
        t[4] = (short)f2bf(f1.x); t[5] = (short)f2bf(f1.y);                           \
        t[6] = (short)f2bf(f1.z); t[7] = (short)f2bf(f1.w);                           \
        dst = t;                                                                      \
    }

// Load A fragments for row-tile rt of THIS wave's row-half (rows p*32+rt*16+r).
#define LOADROW(rt, A0, A1, A2, A3, A4, A5, A6, A7)                                   \
    {                                                                                 \
        const float4* xr4 = (const float4*)(x + (row0 + p * 32 + (rt) * 16 + r) * NM);\
        float ss = 0.f;                                                               \
        LOADFRAG(A0, 0) LOADFRAG(A1, 1) LOADFRAG(A2, 2) LOADFRAG(A3, 3)               \
        LOADFRAG(A4, 4) LOADFRAG(A5, 5) LOADFRAG(A6, 6) LOADFRAG(A7, 7)               \
        ss += __shfl_xor(ss, 16, 64);                                                 \
        ss += __shfl_xor(ss, 32, 64);                                                 \
        if ((w >> 1) == 0 && g == 0) xsl[p * 32 + (rt) * 16 + r] = ss * LOG2E;        \
    }

// One K=32 step across both row-tiles: 1 ds_read_b128 -> 2 MFMA. s must be a literal.
#define CSTEP(s)                                                                      \
    {                                                                                 \
        const short8 b =                                                              \
            *(const short8*)(bp + r * 256 + ((((s) * 4 + g) ^ (r & 7)) * 8));         \
        c0 = __builtin_amdgcn_mfma_f32_16x16x32_bf16(af0##s, b, c0, 0, 0, 0);         \
        c1 = __builtin_amdgcn_mfma_f32_16x16x32_bf16(af1##s, b, c1, 0, 0, 0);         \
    }

#define EPI1(cc, xsv, acref)                                                          \
    acref = fmaf(EXP2F(fmaf(cc, TWO_LOG2E, nb - (xsv))), wgt, acref);

// One 16-center tile: 8 ds_read_b128 -> 16 MFMA -> fused exp/W epilogue (all static).
#define COMPUTE(bufIdx, wcv)                                                          \
    {                                                                                 \
        const unsigned short* bp = &Bt[w][bufIdx][0];                                 \
        floatx4 c0 = {0.f, 0.f, 0.f, 0.f}, c1 = {0.f, 0.f, 0.f, 0.f};                 \
        CSTEP(0) CSTEP(1) CSTEP(2) CSTEP(3) CSTEP(4) CSTEP(5) CSTEP(6) CSTEP(7)       \
        const float nb  = -(wcv).y;                                                   \
        const float wgt = (wcv).x;                                                    \
        EPI1(c0[0], xs0.x, ac0.x) EPI1(c0[1], xs0.y, ac0.y)                           \
        EPI1(c0[2], xs0.z, ac0.z) EPI1(c0[3], xs0.w, ac0.w)                           \
        EPI1(c1[0], xs1.x, ac1.x) EPI1(c1[1], xs1.y, ac1.y)                           \
        EPI1(c1[2], xs1.z, ac1.z) EPI1(c1[3], xs1.w, ac1.w)                           \
    }

#define RED(val, rt, j)                                                               \
    {                                                                                 \
        float v = (val);                                                              \
        v += __shfl_xor(v, 1, 64); v += __shfl_xor(v, 2, 64);                         \
        v += __shfl_xor(v, 4, 64); v += __shfl_xor(v, 8, 64);                         \
        if (r == 0) rowacc[w][(rt) * 16 + g * 4 + (j)] = v;                           \
    }

// 256 blocks (1/CU), 512 threads (8 waves). Block owns 64 rows. Wave w:
// row-half p=w&1 (32 rows -> afrag 64 VGPRs), center slice s=w>>1 (1024 centers,
// 64 tiles). R=2 fits the observed hard 128-arch-VGPR budget (R2-R5: demand ~190
// spilled exactly 512 B/thread regardless of launch-bounds/attrs -> fit, don't fight).
// No main-loop barriers; per-wave counted vmcnt(9) double-buffer pipeline.
__global__ void
__attribute__((amdgpu_flat_work_group_size(512, 512), amdgpu_waves_per_eu(2, 2)))
rbf_main(const float* __restrict__ x,
         const float* __restrict__ bptr,
         float* __restrict__ out) {
    __shared__ __align__(16) unsigned short Bt[8][2][16 * NM];  // 128 KB
    __shared__ float xsl[64];
    __shared__ float rowacc[8][32];

    const int tid  = threadIdx.x;
    const int w    = tid >> 6;
    const int lane = tid & 63;
    const int r    = lane & 15;
    const int g    = lane >> 4;
    const int p    = w & 1;        // row-half
    const int row0 = blockIdx.x * 64;
    const int n0   = (w >> 1) * 1024;   // center slice base

    short8 af00, af01, af02, af03, af04, af05, af06, af07;
    short8 af10, af11, af12, af13, af14, af15, af16, af17;

    LOADROW(0, af00, af01, af02, af03, af04, af05, af06, af07)
    LOADROW(1, af10, af11, af12, af13, af14, af15, af16, af17)
    __syncthreads();

    // per-lane ||x||^2*log2e for this lane's C/D rows: p*32 + rt*16 + g*4 + {0..3}
    const float4 xs0 = *(const float4*)&xsl[p * 32 + 0 * 16 + g * 4];
    const float4 xs1 = *(const float4*)&xsl[p * 32 + 1 * 16 + g * 4];

    float4 ac0 = {0.f, 0.f, 0.f, 0.f};
    float4 ac1 = {0.f, 0.f, 0.f, 0.f};

    // prologue: tile 0 + wc 0 in flight (9 vmem ops outstanding at loop top)
    STAGE(0, 0);
    float2 wcA = g_wc[n0 + r];
    float2 wcB;

    #pragma unroll 1
    for (int i = 0; i < 64; i += 2) {
        // ---- iter i: consume buf0/wcA, prefetch tile i+1 -> buf1 ----
        wcB = g_wc[n0 + ((i + 1) & 63) * 16 + r];
        STAGE((i + 1) & 63, 1);
        asm volatile("s_waitcnt vmcnt(9)" ::: "memory");  // tile i + wc_i drained
        __builtin_amdgcn_sched_barrier(0);
        COMPUTE(0, wcA);
        // ---- iter i+1: consume buf1/wcB, prefetch tile i+2 -> buf0 ----
        wcA = g_wc[n0 + ((i + 2) & 63) * 16 + r];
        STAGE((i + 2) & 63, 0);
        asm volatile("s_waitcnt vmcnt(9)" ::: "memory");
        __builtin_amdgcn_sched_barrier(0);
        COMPUTE(1, wcB);
    }

    // ---- reduce over the 16 column-lanes; combine 4 slices' N-partials ----
    RED(ac0.x, 0, 0) RED(ac0.y, 0, 1) RED(ac0.z, 0, 2) RED(ac0.w, 0, 3)
    RED(ac1.x, 1, 0) RED(ac1.y, 1, 1) RED(ac1.z, 1, 2) RED(ac1.w, 1, 3)
    __syncthreads();

    if (tid < 64) {
        const int pp = tid >> 5;       // row-half
        const int lr = tid & 31;       // row within half
        float logit = bptr[0];
        #pragma unroll
        for (int s = 0; s < 4; ++s) logit += rowacc[s * 2 + pp][lr];
        out[row0 + tid] = 1.f / (1.f + EXP2F(-logit * LOG2E));
    }
}

extern "C" void kernel_launch(void* const* d_in, const int* in_sizes, int n_in,
                              void* d_out, int out_size, void* d_ws, size_t ws_size,
                              hipStream_t stream) {
    const float* x  = (const float*)d_in[0];   // [16384,256]
    const float* xb = (const float*)d_in[1];   // [4096,256]
    const float* W  = (const float*)d_in[2];   // [1,4096]
    const float* b  = (const float*)d_in[3];   // [1]
    float* out = (float*)d_out;                // [16384,1]

    rbf_prep<<<dim3(NB / 4), dim3(256), 0, stream>>>(xb, W);
    rbf_main<<<dim3(NK / 64), dim3(512), 0, stream>>>(x, b, out);
}

// Round 7
// 56.989 us; speedup vs baseline: 1.4373x; 1.0933x over previous
//
#include <hip/hip_runtime.h>
#include <cstdint>

#define NK 16384
#define NB 4096
#define NM 256
#define LOG2E 1.4426950408889634f
#define TWO_LOG2E 2.8853900817779268f

typedef __attribute__((ext_vector_type(8))) short short8;
typedef __attribute__((ext_vector_type(4))) float floatx4;

#if __has_builtin(__builtin_amdgcn_exp2f)
#define EXP2F(x) __builtin_amdgcn_exp2f(x)
#else
#define EXP2F(x) exp2f(x)
#endif

// Static device scratch: bf16 copy of x_basis [4096][256], per-center {W[n], ||c_n||^2*log2e}.
__device__ unsigned short g_xb[NB * NM];   // 2 MB (L2-resident per XCD)
__device__ float2 g_wc[NB];                // 32 KB

__device__ __forceinline__ unsigned short f2bf(float f) {
    unsigned int u = __float_as_uint(f);
    u += 0x7FFFu + ((u >> 16) & 1u);       // RTN-even
    return (unsigned short)(u >> 16);
}

// One wave per x_basis row: convert 256 fp32 -> bf16, compute ||c||^2 * log2e.
__global__ __launch_bounds__(256) void rbf_prep(const float* __restrict__ xb,
                                                const float* __restrict__ W) {
    const int row  = blockIdx.x * 4 + (threadIdx.x >> 6);
    const int lane = threadIdx.x & 63;
    const float4 v = ((const float4*)(xb + row * NM))[lane];
    float ss = v.x * v.x + v.y * v.y + v.z * v.z + v.w * v.w;
    #pragma unroll
    for (int m = 1; m < 64; m <<= 1) ss += __shfl_xor(ss, m, 64);
    ushort4 o;
    o.x = f2bf(v.x); o.y = f2bf(v.y); o.z = f2bf(v.z); o.w = f2bf(v.w);
    *(ushort4*)(g_xb + row * NM + lane * 4) = o;
    if (lane == 0) g_wc[row] = make_float2(W[row], ss * LOG2E);
}

// Stage HALF of one 16-center tile (this wave's 4 chunk-groups; partner stages the
// other 4). LDS dest linear (uniform base + lane*16); bank-conflict swizzle applied
// on the GLOBAL source side (chunk ^= row&7); ds_read applies the same involution.
#define STAGE(t, bufIdx)                                                              \
    {                                                                                 \
        _Pragma("unroll")                                                             \
        for (int j2 = 0; j2 < 4; ++j2) {                                              \
            const int j  = p * 4 + j2;         /* chunk-group 0..7, split by p */     \
            const int q  = j * 64 + lane;      /* 16B-chunk index within tile */      \
            const int rr = q >> 5;             /* center row 0..15 */                 \
            const int cc = q & 31;             /* 16B chunk within row */             \
            const unsigned short* srcp =                                              \
                g_xb + (n0 + (t) * 16 + rr) * NM + ((cc ^ (rr & 7)) * 8);             \
            unsigned short* dstp = &Bt[gr][bufIdx][j * 512];                          \
            __builtin_amdgcn_global_load_lds(                                         \
                (const __attribute__((address_space(1))) void*)srcp,                  \
                (__attribute__((address_space(3))) void*)dstp, 16, 0, 0);             \
        }                                                                             \
    }

// ---- A prologue helpers: NAMED fragments only (no runtime-indexed arrays).
#define LOADFRAG(dst, s)                                                              \
    {                                                                                 \
        const float4 f0 = xr4[(s) * 8 + g * 2];                                       \
        const float4 f1 = xr4[(s) * 8 + g * 2 + 1];                                   \
        ss += f0.x * f0.x + f0.y * f0.y + f0.z * f0.z + f0.w * f0.w                   \
            + f1.x * f1.x + f1.y * f1.y + f1.z * f1.z + f1.w * f1.w;                  \
        short8 t;                                                                     \
        t[0] = (short)f2bf(f0.x); t[1] = (short)f2bf(f0.y);                           \
        t[2] = (short)f2bf(f0.z); t[3] = (short)f2bf(f0.w);                           \
        t[4] = (short)f2bf(f1.x); t[5] = (short)f2bf(f1.y);                           \
        t[6] = (short)f2bf(f1.z); t[7] = (short)f2bf(f1.w);                           \
        dst = t;                                                                      \
    }

// Load A fragments for row-tile rt of THIS wave's row-half (rows p*32+rt*16+r).
#define LOADROW(rt, A0, A1, A2, A3, A4, A5, A6, A7)                                   \
    {                                                                                 \
        const float4* xr4 = (const float4*)(x + (row0 + p * 32 + (rt) * 16 + r) * NM);\
        float ss = 0.f;                                                               \
        LOADFRAG(A0, 0) LOADFRAG(A1, 1) LOADFRAG(A2, 2) LOADFRAG(A3, 3)               \
        LOADFRAG(A4, 4) LOADFRAG(A5, 5) LOADFRAG(A6, 6) LOADFRAG(A7, 7)               \
        ss += __shfl_xor(ss, 16, 64);                                                 \
        ss += __shfl_xor(ss, 32, 64);                                                 \
        if (gr == 0 && g == 0) xsl[p * 32 + (rt) * 16 + r] = ss * LOG2E;              \
    }

// One K=32 step across both row-tiles: 1 ds_read_b128 -> 2 MFMA. s must be a literal.
#define CSTEP(s)                                                                      \
    {                                                                                 \
        const short8 b =                                                              \
            *(const short8*)(bp + r * 256 + ((((s) * 4 + g) ^ (r & 7)) * 8));         \
        c0 = __builtin_amdgcn_mfma_f32_16x16x32_bf16(af0##s, b, c0, 0, 0, 0);         \
        c1 = __builtin_amdgcn_mfma_f32_16x16x32_bf16(af1##s, b, c1, 0, 0, 0);         \
    }

#define EPI1(cc, xsv, acref)                                                          \
    acref = fmaf(EXP2F(fmaf(cc, TWO_LOG2E, nb - (xsv))), wgt, acref);

// One 16-center tile: 8 ds_read_b128 -> 16 MFMA -> fused exp/W epilogue (all static).
#define COMPUTE(bufIdx, wcv)                                                          \
    {                                                                                 \
        const unsigned short* bp = &Bt[gr][bufIdx][0];                                \
        floatx4 c0 = {0.f, 0.f, 0.f, 0.f}, c1 = {0.f, 0.f, 0.f, 0.f};                 \
        CSTEP(0) CSTEP(1) CSTEP(2) CSTEP(3) CSTEP(4) CSTEP(5) CSTEP(6) CSTEP(7)       \
        const float nb  = -(wcv).y;                                                   \
        const float wgt = (wcv).x;                                                    \
        EPI1(c0[0], xs0.x, ac0.x) EPI1(c0[1], xs0.y, ac0.y)                           \
        EPI1(c0[2], xs0.z, ac0.z) EPI1(c0[3], xs0.w, ac0.w)                           \
        EPI1(c1[0], xs1.x, ac1.x) EPI1(c1[1], xs1.y, ac1.y)                           \
        EPI1(c1[2], xs1.z, ac1.z) EPI1(c1[3], xs1.w, ac1.w)                           \
    }

// One pipeline sub-iteration for tile t (buf/wc names are literals):
// load wc(t+2), stage tile t+2 (depth-2 ahead), drain OWN tile-t ops (vmcnt(10)
// = 2 newer tiles' 5 vmem each stay in flight), raw barrier (partner's half +
// all groups synced -- NO vmcnt(0) drain), then compute tile t.
#define SUBITER(t_ahead, bufStage, bufUse, wcLoad, wcUse)                             \
    wcLoad = g_wc[n0 + ((t_ahead) & 63) * 16 + r];                                    \
    STAGE((t_ahead) & 63, bufStage);                                                  \
    asm volatile("s_waitcnt vmcnt(10)" ::: "memory");                                 \
    __builtin_amdgcn_s_barrier();                                                     \
    __builtin_amdgcn_sched_barrier(0);                                                \
    COMPUTE(bufUse, wcUse);

// 256 blocks (1/CU), 512 threads (8 waves). Block owns 64 rows. Wave pair
// (2s, 2s+1) shares center slice s (1024 centers, 64 tiles): p=w&1 row-half,
// each wave stages half of each shared tile -> per-CU L2->LDS staging halves
// to 2 MB (R6 was staging-BW-bound at 4 MB: MfmaUtil 23%, HBM 3%).
// 4-deep shared buffers, counted vmcnt(10), raw barriers, lockstep 64 rounds.
__global__ void
__attribute__((amdgpu_flat_work_group_size(512, 512), amdgpu_waves_per_eu(2, 2)))
rbf_main(const float* __restrict__ x,
         const float* __restrict__ bptr,
         float* __restrict__ out) {
    __shared__ __align__(16) unsigned short Bt[4][4][16 * NM];  // [group][buf] 128 KB
    __shared__ __align__(16) float xsl[64];
    __shared__ float rowacc[8][32];

    const int tid  = threadIdx.x;
    const int w    = tid >> 6;
    const int lane = tid & 63;
    const int r    = lane & 15;
    const int g    = lane >> 4;
    const int p    = w & 1;            // row-half within pair
    const int gr   = w >> 1;           // pair/group id 0..3
    const int row0 = blockIdx.x * 64;
    const int n0   = gr * 1024;        // shared center-slice base

    short8 af00, af01, af02, af03, af04, af05, af06, af07;
    short8 af10, af11, af12, af13, af14, af15, af16, af17;

    LOADROW(0, af00, af01, af02, af03, af04, af05, af06, af07)
    LOADROW(1, af10, af11, af12, af13, af14, af15, af16, af17)
    __syncthreads();

    // per-lane ||x||^2*log2e for this lane's C/D rows: p*32 + rt*16 + g*4 + {0..3}
    const float4 xs0 = *(const float4*)&xsl[p * 32 + 0 * 16 + g * 4];
    const float4 xs1 = *(const float4*)&xsl[p * 32 + 1 * 16 + g * 4];

    float4 ac0 = {0.f, 0.f, 0.f, 0.f};
    float4 ac1 = {0.f, 0.f, 0.f, 0.f};

    // prologue: tiles 0,1 + wc(0),wc(1) in flight (10 vmem ops outstanding)
    STAGE(0, 0);
    float2 wcA = g_wc[n0 + 0 * 16 + r];
    STAGE(1, 1);
    float2 wcB = g_wc[n0 + 1 * 16 + r];
    float2 wcC, wcD;

    #pragma unroll 1
    for (int t = 0; t < 64; t += 4) {
        SUBITER(t + 2, 2, 0, wcC, wcA)   // compute tile t
        SUBITER(t + 3, 3, 1, wcD, wcB)   // compute tile t+1
        SUBITER(t + 4, 0, 2, wcA, wcC)   // compute tile t+2
        SUBITER(t + 5, 1, 3, wcB, wcD)   // compute tile t+3
    }

    // ---- reduce over the 16 column-lanes; combine 4 slices' N-partials ----
    RED_DECL:;
    {
        #define RED(val, rt, j)                                                       \
            {                                                                         \
                float v = (val);                                                      \
                v += __shfl_xor(v, 1, 64); v += __shfl_xor(v, 2, 64);                 \
                v += __shfl_xor(v, 4, 64); v += __shfl_xor(v, 8, 64);                 \
                if (r == 0) rowacc[w][(rt) * 16 + g * 4 + (j)] = v;                   \
            }
        RED(ac0.x, 0, 0) RED(ac0.y, 0, 1) RED(ac0.z, 0, 2) RED(ac0.w, 0, 3)
        RED(ac1.x, 1, 0) RED(ac1.y, 1, 1) RED(ac1.z, 1, 2) RED(ac1.w, 1, 3)
    }
    __syncthreads();

    if (tid < 64) {
        const int pp = tid >> 5;       // row-half
        const int lr = tid & 31;       // row within half
        float logit = bptr[0];
        #pragma unroll
        for (int s = 0; s < 4; ++s) logit += rowacc[s * 2 + pp][lr];
        out[row0 + tid] = 1.f / (1.f + EXP2F(-logit * LOG2E));
    }
}

extern "C" void kernel_launch(void* const* d_in, const int* in_sizes, int n_in,
                              void* d_out, int out_size, void* d_ws, size_t ws_size,
                              hipStream_t stream) {
    const float* x  = (const float*)d_in[0];   // [16384,256]
    const float* xb = (const float*)d_in[1];   // [4096,256]
    const float* W  = (const float*)d_in[2];   // [1,4096]
    const float* b  = (const float*)d_in[3];   // [1]
    float* out = (float*)d_out;                // [16384,1]

    rbf_prep<<<dim3(NB / 4), dim3(256), 0, stream>>>(xb, W);
    rbf_main<<<dim3(NK / 64), dim3(512), 0, stream>>>(x, b, out);
}